// Round 8
// baseline (161.267 us; speedup 1.0000x reference)
//
#include <hip/hip_runtime.h>
#include <math.h>

#define NTOK 16384
#define DIN  128
#define NCH  512
#define CHL  32   // tokens per chunk
#define NG   32   // carry-scan groups
#define GCH  16   // chunks per group (NCH/NG)

__device__ __forceinline__ float silu_f(float x)    { return x / (1.f + __expf(-x)); }
__device__ __forceinline__ float softplus_f(float x){ return (x > 20.f) ? x : log1pf(__expf(x)); }

// ---------------- K1: LayerNorm(64) + in_proj (64 -> 256) as W-in-registers GEMV.
// thread = output row d (256 rows); W row in 16 float4 VGPRs; token rows broadcast from LDS.
__global__ __launch_bounds__(256) void k1_ln_inproj(
    const float* __restrict__ x, const float* __restrict__ lnw,
    const float* __restrict__ lnb, const float* __restrict__ Win,
    float* __restrict__ xin, float* __restrict__ zbuf)
{
  __shared__ __align__(16) float bufA[64*68];   // x[c][tok]
  __shared__ __align__(16) float bufB[64*68];   // tln[tok][c]
  __shared__ float ps[256], pq[256], mu[64], rs[64];

  int t = threadIdx.x;
  int b  = blockIdx.x >> 8;            // 256 tiles of 64 tokens per batch
  int n0 = (blockIdx.x & 255) << 6;
  const float* xb = x + ((size_t)b*64)*NTOK;

  // W row -> registers (L2-resident; issue early)
  float4 wreg[16];
  #pragma unroll
  for (int i = 0; i < 16; ++i)
    wreg[i] = *(const float4*)&Win[t*64 + i*4];

  // load [c][tok] + LN partials
  int tok = t & 63, quad = t >> 6;
  float s0 = 0.f, s1 = 0.f;
  for (int i = 0; i < 16; ++i) {
    int c = i*4 + quad;
    float v = xb[(size_t)c*NTOK + n0 + tok];
    bufA[c*68 + tok] = v;
    s0 += v; s1 += v*v;
  }
  ps[t] = s0; pq[t] = s1;
  __syncthreads();
  if (t < 64) {
    float m = ps[t] + ps[64+t] + ps[128+t] + ps[192+t];
    float q = pq[t] + pq[64+t] + pq[128+t] + pq[192+t];
    m *= 0.015625f;
    q = q*0.015625f - m*m;
    mu[t] = m; rs[t] = rsqrtf(q + 1e-5f);
  }
  __syncthreads();

  // transpose + LN: bufA[c][tok] -> bufB[tok][c]
  {
    int c = t & 63, tq = t >> 6;
    float wv = lnw[c], bv = lnb[c];
    #pragma unroll
    for (int i = 0; i < 4; ++i) {
      int tok4 = tq*4 + i;
      float4 f = *(const float4*)&bufA[c*68 + tok4*4];
      float vals[4] = {f.x, f.y, f.z, f.w};
      #pragma unroll
      for (int k = 0; k < 4; ++k) {
        int tk = tok4*4 + k;
        bufB[tk*68 + c] = (vals[k] - mu[tk]) * rs[tk] * wv + bv;
      }
    }
  }
  __syncthreads();

  // GEMV over 64 tokens: broadcast tln row, fma against wreg.
  bool zhalf = (t >= 128);
  float* outp = zhalf ? zbuf : xin;
  int d = t & 127;
  long nbase = (long)b*NTOK + n0;
  for (int n = 0; n < 64; n += 2) {
    const float* r0 = &bufB[n*68];
    const float* r1 = r0 + 68;
    float a0[4] = {0.f,0.f,0.f,0.f}, a1[4] = {0.f,0.f,0.f,0.f};
    #pragma unroll
    for (int i = 0; i < 4; ++i) {
      #pragma unroll
      for (int p = 0; p < 4; ++p) {
        int c4 = p*4 + i;
        float4 wv = wreg[c4];
        float4 t0 = *(const float4*)&r0[c4*4];
        a0[p] += t0.x*wv.x + t0.y*wv.y + t0.z*wv.z + t0.w*wv.w;
        float4 t1 = *(const float4*)&r1[c4*4];
        a1[p] += t1.x*wv.x + t1.y*wv.y + t1.z*wv.z + t1.w*wv.w;
      }
    }
    float y0 = (a0[0] + a0[1]) + (a0[2] + a0[3]);
    float y1 = (a1[0] + a1[1]) + (a1[2] + a1[3]);
    if (zhalf) { y0 = silu_f(y0); y1 = silu_f(y1); }
    outp[(nbase + n    )*128 + d] = y0;
    outp[(nbase + n + 1)*128 + d] = y1;
  }
}

// ---------------- K2: depthwise causal conv(k=4) + SiLU, 8-token sliding window/thread
__global__ __launch_bounds__(256) void k2_conv(
    const float* __restrict__ xin, const float* __restrict__ cw,
    const float* __restrict__ cb, float* __restrict__ u)
{
  int t = threadIdx.x;
  int d = t & 127;
  long g0 = (long)blockIdx.x*16 + (t >> 7)*8;   // 16 tok/block
  int n = (int)(g0 & (NTOK-1));
  float w0 = cw[d*4], w1 = cw[d*4+1], w2 = cw[d*4+2], w3 = cw[d*4+3];
  float cbv = cb[d];
  float xa = (n >= 3) ? xin[(g0-3)*128 + d] : 0.f;
  float xb = (n >= 2) ? xin[(g0-2)*128 + d] : 0.f;
  float xc = (n >= 1) ? xin[(g0-1)*128 + d] : 0.f;
  #pragma unroll
  for (int j = 0; j < 8; ++j) {
    float xd = xin[(g0+j)*128 + d];
    u[(g0+j)*128 + d] = silu_f(w0*xa + w1*xb + w2*xc + w3*xd + cbv);
    xa = xb; xb = xc; xc = xd;
  }
}

// ---------------- K3: x_proj (36 outs) + dt_proj + softplus (reduction-free)
__global__ __launch_bounds__(256) void k3_xproj_dt(
    const float* __restrict__ u, const float* __restrict__ Wx,
    const float* __restrict__ Wdt, const float* __restrict__ db,
    float* __restrict__ dt, float* __restrict__ Bm, float* __restrict__ Cm)
{
  __shared__ __align__(16) float wx[36*128];
  __shared__ float wdtT[4*128];
  __shared__ __align__(16) float xdbl[64*40];
  int t = threadIdx.x;
  for (int i = t; i < 1152; i += 256)
    *(float4*)&wx[i*4] = *(const float4*)&Wx[i*4];
  for (int i = t; i < 512; i += 256)
    wdtT[(i&3)*128 + (i>>2)] = Wdt[i];
  __syncthreads();

  long tok0 = (long)blockIdx.x * 64;
  int tok = t & 63, grp = t >> 6;
  const float* urow = u + (tok0 + tok)*128;

  float acc[9];
  #pragma unroll
  for (int e = 0; e < 9; ++e) acc[e] = 0.f;
  #pragma unroll 8
  for (int d4 = 0; d4 < 32; ++d4) {
    float4 uv = *(const float4*)&urow[d4*4];
    #pragma unroll
    for (int e = 0; e < 9; ++e) {
      float4 wv = *(const float4*)&wx[(grp*9+e)*128 + d4*4];
      acc[e] += uv.x*wv.x + uv.y*wv.y + uv.z*wv.z + uv.w*wv.w;
    }
  }
  #pragma unroll
  for (int e = 0; e < 9; ++e) xdbl[tok*40 + grp*9 + e] = acc[e];
  __syncthreads();

  {
    int tk = t >> 2, q = t & 3;
    float4 bv = *(const float4*)&xdbl[tk*40 + 4  + q*4];
    float4 cv = *(const float4*)&xdbl[tk*40 + 20 + q*4];
    *(float4*)&Bm[(tok0+tk)*16 + q*4] = bv;
    *(float4*)&Cm[(tok0+tk)*16 + q*4] = cv;
  }
  int d = t & 127, th = t >> 7;
  float w0 = wdtT[d], w1 = wdtT[128+d], w2 = wdtT[256+d], w3 = wdtT[384+d];
  float bias = db[d];
  for (int j = 0; j < 32; ++j) {
    int tk = th*32 + j;
    float a = bias + xdbl[tk*40]*w0 + xdbl[tk*40+1]*w1
                   + xdbl[tk*40+2]*w2 + xdbl[tk*40+3]*w3;
    dt[(tok0+tk)*128 + d] = softplus_f(a);
  }
}

// ---------------- K4A: per-chunk local scan -> carries. thread = (d = t>>1, s-half = t&1)
__global__ __launch_bounds__(256) void k4a_local(
    const float* __restrict__ dt, const float* __restrict__ u,
    const float* __restrict__ Bm, const float* __restrict__ Alog,
    float* __restrict__ carP, float* __restrict__ carH)
{
  int t = threadIdx.x;
  int d = t >> 1, sh = t & 1;
  int b = blockIdx.x / NCH, ch = blockIdx.x % NCH;
  long nb = (long)b*NTOK + (long)ch*CHL;
  float A[8], h[8], P[8];
  #pragma unroll
  for (int k = 0; k < 2; ++k) {
    float4 a = *(const float4*)&Alog[d*16 + sh*8 + k*4];
    A[k*4+0] = -__expf(a.x); A[k*4+1] = -__expf(a.y);
    A[k*4+2] = -__expf(a.z); A[k*4+3] = -__expf(a.w);
  }
  #pragma unroll
  for (int s = 0; s < 8; ++s) { h[s] = 0.f; P[s] = 1.f; }
  for (int i = 0; i < CHL; ++i) {
    long n = nb + i;
    float dtv = dt[n*128 + d];
    float uv  = u [n*128 + d];
    float du  = dtv * uv;
    float Bv[8];
    #pragma unroll
    for (int k = 0; k < 2; ++k) {
      float4 v = *(const float4*)&Bm[n*16 + sh*8 + k*4];
      Bv[k*4]=v.x; Bv[k*4+1]=v.y; Bv[k*4+2]=v.z; Bv[k*4+3]=v.w;
    }
    #pragma unroll
    for (int s = 0; s < 8; ++s) {
      float dA = __expf(dtv * A[s]);
      h[s] = dA*h[s] + du*Bv[s];
      P[s] *= dA;
    }
  }
  long cbs = ((long)(b*NCH + ch)*128 + d)*16 + sh*8;
  #pragma unroll
  for (int k = 0; k < 2; ++k) {
    *(float4*)&carP[cbs + k*4] = make_float4(P[k*4],P[k*4+1],P[k*4+2],P[k*4+3]);
    *(float4*)&carH[cbs + k*4] = make_float4(h[k*4],h[k*4+1],h[k*4+2],h[k*4+3]);
  }
}

// ---------------- K4B1: scan GCH-chunk groups; exclusive prefixes in place + group carries
__global__ __launch_bounds__(256) void k4b1_group(
    float* __restrict__ cP, float* __restrict__ cH,
    float* __restrict__ Pg, float* __restrict__ Hg)
{
  int idx = blockIdx.x*256 + threadIdx.x;
  int rem = idx & 2047;
  int g   = (idx >> 11) & (NG-1);
  int b   = idx >> 16;
  float P = 1.f, H = 0.f;
  long base = ((long)b*NCH + g*GCH)*2048 + rem;
  #pragma unroll 4
  for (int j = 0; j < GCH; ++j) {
    long a = base + (long)j*2048;
    float p = cP[a], h = cH[a];
    cP[a] = P; cH[a] = H;
    H = p*H + h;
    P = p*P;
  }
  long ga = ((long)b*NG + g)*2048 + rem;
  Pg[ga] = P; Hg[ga] = H;
}

// ---------------- K4B2: scan over NG group carries -> exclusive Hg in place
__global__ __launch_bounds__(256) void k4b2_carry(
    const float* __restrict__ Pg, float* __restrict__ Hg)
{
  int idx = blockIdx.x*256 + threadIdx.x;
  int b = idx >> 11, rem = idx & 2047;
  float H = 0.f;
  #pragma unroll 4
  for (int g = 0; g < NG; ++g) {
    long a = ((long)b*NG + g)*2048 + rem;
    float p = Pg[a], h = Hg[a];
    Hg[a] = H;
    H = p*H + h;
  }
}

// ---------------- K4C: chunk scan w/ carry-in + C-contraction + uD + *silu(z).
// thread = (d = t>>1, s-half = t&1); y combined via shfl_xor(1).
__global__ __launch_bounds__(256) void k4c_apply(
    const float* __restrict__ dt, const float* __restrict__ u,
    const float* __restrict__ Bm, const float* __restrict__ Cm,
    const float* __restrict__ Alog, const float* __restrict__ Dp,
    const float* __restrict__ zs, const float* __restrict__ pPre,
    const float* __restrict__ hPre, const float* __restrict__ Hg,
    float* __restrict__ yz)
{
  int t = threadIdx.x;
  int d = t >> 1, sh = t & 1;
  int b = blockIdx.x / NCH, ch = blockIdx.x % NCH;
  long nb = (long)b*NTOK + (long)ch*CHL;
  float A[8], h[8];
  #pragma unroll
  for (int k = 0; k < 2; ++k) {
    float4 a = *(const float4*)&Alog[d*16 + sh*8 + k*4];
    A[k*4+0] = -__expf(a.x); A[k*4+1] = -__expf(a.y);
    A[k*4+2] = -__expf(a.z); A[k*4+3] = -__expf(a.w);
  }
  long cbs = ((long)(b*NCH + ch)*128 + d)*16 + sh*8;
  long gbs = ((long)b*NG + (ch >> 4))*2048 + d*16 + sh*8;
  #pragma unroll
  for (int k = 0; k < 2; ++k) {
    float4 hp = *(const float4*)&hPre[cbs + k*4];
    float4 pp = *(const float4*)&pPre[cbs + k*4];
    float4 gi = *(const float4*)&Hg[gbs + k*4];
    h[k*4+0] = hp.x + pp.x*gi.x; h[k*4+1] = hp.y + pp.y*gi.y;
    h[k*4+2] = hp.z + pp.z*gi.z; h[k*4+3] = hp.w + pp.w*gi.w;
  }
  float Dv = Dp[d];
  for (int i = 0; i < CHL; ++i) {
    long n = nb + i;
    float dtv = dt[n*128 + d];
    float uv  = u [n*128 + d];
    float du  = dtv * uv;
    float Bv[8], Cv[8];
    #pragma unroll
    for (int k = 0; k < 2; ++k) {
      float4 v = *(const float4*)&Bm[n*16 + sh*8 + k*4];
      Bv[k*4]=v.x; Bv[k*4+1]=v.y; Bv[k*4+2]=v.z; Bv[k*4+3]=v.w;
      float4 w = *(const float4*)&Cm[n*16 + sh*8 + k*4];
      Cv[k*4]=w.x; Cv[k*4+1]=w.y; Cv[k*4+2]=w.z; Cv[k*4+3]=w.w;
    }
    float y = 0.f;
    #pragma unroll
    for (int s = 0; s < 8; ++s) {
      float dA = __expf(dtv * A[s]);
      h[s] = dA*h[s] + du*Bv[s];
      y += h[s]*Cv[s];
    }
    y += __shfl_xor(y, 1);
    if (sh == 0)
      yz[n*128 + d] = (y + uv*Dv) * zs[n*128 + d];
  }
}

// ---------------- K6: out_proj (128 -> 64) + bias, write (B,C,N)
__global__ __launch_bounds__(256) void k6_outproj(
    const float* __restrict__ yz, const float* __restrict__ Wout,
    const float* __restrict__ ob, float* __restrict__ out)
{
  __shared__ __align__(16) float wo[64*132];
  __shared__ __align__(16) float yl[32*132];
  int t = threadIdx.x;
  long tok0 = (long)blockIdx.x * 32;
  for (int i = 0; i < 8; ++i) {
    int g = i*256 + t; int c = g >> 5, q = g & 31;
    *(float4*)&wo[c*132 + q*4] = *(const float4*)&Wout[c*128 + q*4];
  }
  for (int i = 0; i < 4; ++i) {
    int g = i*256 + t; int tok = g >> 5, q = g & 31;
    *(float4*)&yl[tok*132 + q*4] = *(const float4*)&yz[(tok0 + tok)*128 + q*4];
  }
  __syncthreads();
  int tp = t & 15;
  int tg = t >> 4;
  float acc[4][2] = {{0.f}};
  for (int d4 = 0; d4 < 32; ++d4) {
    float4 y0 = *(const float4*)&yl[tg*132 + d4*4];
    float4 y1 = *(const float4*)&yl[(tg+16)*132 + d4*4];
    #pragma unroll
    for (int cc = 0; cc < 4; ++cc) {
      float4 wv = *(const float4*)&wo[(tp + 16*cc)*132 + d4*4];
      acc[cc][0] += wv.x*y0.x + wv.y*y0.y + wv.z*y0.z + wv.w*y0.w;
      acc[cc][1] += wv.x*y1.x + wv.y*y1.y + wv.z*y1.z + wv.w*y1.w;
    }
  }
  int b  = (int)(tok0 / NTOK);
  long n0 = tok0 % NTOK;
  #pragma unroll
  for (int cc = 0; cc < 4; ++cc) {
    int c = tp + 16*cc;
    float bias = ob[c];
    out[((long)b*64 + c)*NTOK + n0 + tg     ] = acc[cc][0] + bias;
    out[((long)b*64 + c)*NTOK + n0 + tg + 16] = acc[cc][1] + bias;
  }
}

extern "C" void kernel_launch(void* const* d_in, const int* in_sizes, int n_in,
                              void* d_out, int out_size, void* d_ws, size_t ws_size,
                              hipStream_t stream)
{
  (void)in_sizes; (void)n_in; (void)out_size; (void)ws_size;
  const float* x    = (const float*)d_in[0];
  const float* lnw  = (const float*)d_in[1];
  const float* lnb  = (const float*)d_in[2];
  const float* Win  = (const float*)d_in[3];
  const float* cw   = (const float*)d_in[4];
  const float* cb   = (const float*)d_in[5];
  const float* Wx   = (const float*)d_in[6];
  const float* Wdt  = (const float*)d_in[7];
  const float* db   = (const float*)d_in[8];
  const float* Alog = (const float*)d_in[9];
  const float* Dp   = (const float*)d_in[10];
  const float* Wout = (const float*)d_in[11];
  const float* ob   = (const float*)d_in[12];
  float* out = (float*)d_out;

  float* w   = (float*)d_ws;
  float* xin = w;                 // 4,194,304
  float* z   = w + 4194304;       // 4,194,304
  float* u   = w + 8388608;       // 4,194,304
  float* dt  = w + 12582912;      // 4,194,304
  float* Bm  = w + 16777216;      // 524,288
  float* Cm  = w + 17301504;      // 524,288
  float* cP  = w + 17825792;      // 2,097,152 (becomes exclusive P-prefix)
  float* cH  = w + 19922944;      // 2,097,152 (becomes exclusive h-prefix)
  float* Pg  = w + 22020096;      // 131,072
  float* Hg  = w + 22151168;      // 131,072
  float* yz  = w + 22282240;      // 4,194,304

  k1_ln_inproj<<<512, 256, 0, stream>>>(x, lnw, lnb, Win, xin, z);
  k2_conv     <<<2048,256, 0, stream>>>(xin, cw, cb, u);
  k3_xproj_dt <<<512, 256, 0, stream>>>(u, Wx, Wdt, db, dt, Bm, Cm);
  k4a_local   <<<1024,256, 0, stream>>>(dt, u, Bm, Alog, cP, cH);
  k4b1_group  <<<512, 256, 0, stream>>>(cP, cH, Pg, Hg);
  k4b2_carry  <<<16,  256, 0, stream>>>(Pg, Hg);
  k4c_apply   <<<1024,256, 0, stream>>>(dt, u, Bm, Cm, Alog, Dp, z, cP, cH, Hg, yz);
  k6_outproj  <<<1024,256, 0, stream>>>(yz, Wout, ob, out);
}

// Round 9
// 148.793 us; speedup vs baseline: 1.0838x; 1.0838x over previous
//
#include <hip/hip_runtime.h>
#include <math.h>

#define NTOK 16384
#define DIN  128
#define NCH  512
#define CHL  32   // tokens per chunk
#define NG   32   // carry-scan groups
#define GCH  16   // chunks per group (NCH/NG)

__device__ __forceinline__ float silu_f(float x)    { return x / (1.f + __expf(-x)); }
__device__ __forceinline__ float softplus_f(float x){ return (x > 20.f) ? x : log1pf(__expf(x)); }

// ---------------- K1: LayerNorm(64) + in_proj (64 -> 256), register-tiled 8tok x 4d.
// bufW (128x68) aliases phase-1 x[c][tok] in its lower half; W staged per 128-row half.
__global__ __launch_bounds__(256) void k1_ln_inproj(
    const float* __restrict__ x, const float* __restrict__ lnw,
    const float* __restrict__ lnb, const float* __restrict__ Win,
    float* __restrict__ xin, float* __restrict__ zbuf)
{
  __shared__ __align__(16) float bufW[128*68];  // 34.8 KB: phase1 x[c][tok] (c<64), then W-half [d][c]
  __shared__ __align__(16) float bufB[64*68];   // 17.4 KB: tln[tok][c]
  __shared__ float ps[256], pq[256], mu[64], rs[64];

  int t = threadIdx.x;
  int b  = blockIdx.x >> 8;            // 256 tiles of 64 tokens per batch
  int n0 = (blockIdx.x & 255) << 6;
  const float* xb = x + ((size_t)b*64)*NTOK;

  // phase 1: load x [c][tok] + LN partials
  int tok = t & 63, quad = t >> 6;
  float s0 = 0.f, s1 = 0.f;
  for (int i = 0; i < 16; ++i) {
    int c = i*4 + quad;
    float v = xb[(size_t)c*NTOK + n0 + tok];
    bufW[c*68 + tok] = v;
    s0 += v; s1 += v*v;
  }
  ps[t] = s0; pq[t] = s1;
  __syncthreads();
  if (t < 64) {
    float m = ps[t] + ps[64+t] + ps[128+t] + ps[192+t];
    float q = pq[t] + pq[64+t] + pq[128+t] + pq[192+t];
    m *= 0.015625f;
    q = q*0.015625f - m*m;
    mu[t] = m; rs[t] = rsqrtf(q + 1e-5f);
  }
  __syncthreads();

  // phase 2: transpose + LN: bufW[c][tok] -> bufB[tok][c]
  {
    int c = t & 63, tq = t >> 6;
    float wv = lnw[c], bv = lnb[c];
    #pragma unroll
    for (int i = 0; i < 4; ++i) {
      int tok4 = tq*4 + i;
      float4 f = *(const float4*)&bufW[c*68 + tok4*4];
      float vals[4] = {f.x, f.y, f.z, f.w};
      #pragma unroll
      for (int k = 0; k < 4; ++k) {
        int tk = tok4*4 + k;
        bufB[tk*68 + c] = (vals[k] - mu[tk]) * rs[tk] * wv + bv;
      }
    }
  }

  // phase 3: two W halves; thread tile = 8 tok x 4 d.
  int tokg = t & 7, dg = t >> 3;       // tokg 0..7, dg 0..31
  const float4* TB = (const float4*)bufB;
  const float4* TW = (const float4*)bufW;
  long nbase = (long)b*NTOK + n0;
  for (int half = 0; half < 2; ++half) {
    __syncthreads();                   // bufW free (x consumed / prev W done)
    {
      const float4* Wg = (const float4*)&Win[(half << 7)*64];
      #pragma unroll
      for (int i = 0; i < 8; ++i) {
        int idx = i*256 + t;           // 2048 float4 = 128 rows x 16
        int row = idx >> 4, q = idx & 15;
        *(float4*)&bufW[row*68 + q*4] = Wg[row*16 + q];
      }
    }
    __syncthreads();
    float acc[8][4];
    #pragma unroll
    for (int i = 0; i < 8; ++i)
      #pragma unroll
      for (int j = 0; j < 4; ++j) acc[i][j] = 0.f;
    #pragma unroll 4
    for (int c4 = 0; c4 < 16; ++c4) {
      float4 tv[8], wv[4];
      #pragma unroll
      for (int i = 0; i < 8; ++i) tv[i] = TB[(tokg + 8*i)*17 + c4];
      #pragma unroll
      for (int j = 0; j < 4; ++j) wv[j] = TW[(dg + 32*j)*17 + c4];
      #pragma unroll
      for (int i = 0; i < 8; ++i)
        #pragma unroll
        for (int j = 0; j < 4; ++j)
          acc[i][j] += tv[i].x*wv[j].x + tv[i].y*wv[j].y
                     + tv[i].z*wv[j].z + tv[i].w*wv[j].w;
    }
    #pragma unroll
    for (int i = 0; i < 8; ++i) {
      long n = nbase + tokg + 8*i;
      #pragma unroll
      for (int j = 0; j < 4; ++j) {
        int d = dg + 32*j;
        if (half == 0) xin[n*128 + d] = acc[i][j];
        else           zbuf[n*128 + d] = silu_f(acc[i][j]);
      }
    }
  }
}

// ---------------- K2: depthwise causal conv(k=4) + SiLU, 8-token sliding window/thread
__global__ __launch_bounds__(256) void k2_conv(
    const float* __restrict__ xin, const float* __restrict__ cw,
    const float* __restrict__ cb, float* __restrict__ u)
{
  int t = threadIdx.x;
  int d = t & 127;
  long g0 = (long)blockIdx.x*16 + (t >> 7)*8;   // 16 tok/block
  int n = (int)(g0 & (NTOK-1));
  float w0 = cw[d*4], w1 = cw[d*4+1], w2 = cw[d*4+2], w3 = cw[d*4+3];
  float cbv = cb[d];
  float xa = (n >= 3) ? xin[(g0-3)*128 + d] : 0.f;
  float xb = (n >= 2) ? xin[(g0-2)*128 + d] : 0.f;
  float xc = (n >= 1) ? xin[(g0-1)*128 + d] : 0.f;
  #pragma unroll
  for (int j = 0; j < 8; ++j) {
    float xd = xin[(g0+j)*128 + d];
    u[(g0+j)*128 + d] = silu_f(w0*xa + w1*xb + w2*xc + w3*xd + cbv);
    xa = xb; xb = xc; xc = xd;
  }
}

// ---------------- K3: x_proj (36 outs) + dt_proj + softplus (reduction-free)
__global__ __launch_bounds__(256) void k3_xproj_dt(
    const float* __restrict__ u, const float* __restrict__ Wx,
    const float* __restrict__ Wdt, const float* __restrict__ db,
    float* __restrict__ dt, float* __restrict__ Bm, float* __restrict__ Cm)
{
  __shared__ __align__(16) float wx[36*128];
  __shared__ float wdtT[4*128];
  __shared__ __align__(16) float xdbl[64*40];
  int t = threadIdx.x;
  for (int i = t; i < 1152; i += 256)
    *(float4*)&wx[i*4] = *(const float4*)&Wx[i*4];
  for (int i = t; i < 512; i += 256)
    wdtT[(i&3)*128 + (i>>2)] = Wdt[i];
  __syncthreads();

  long tok0 = (long)blockIdx.x * 64;
  int tok = t & 63, grp = t >> 6;
  const float* urow = u + (tok0 + tok)*128;

  float acc[9];
  #pragma unroll
  for (int e = 0; e < 9; ++e) acc[e] = 0.f;
  #pragma unroll 8
  for (int d4 = 0; d4 < 32; ++d4) {
    float4 uv = *(const float4*)&urow[d4*4];
    #pragma unroll
    for (int e = 0; e < 9; ++e) {
      float4 wv = *(const float4*)&wx[(grp*9+e)*128 + d4*4];
      acc[e] += uv.x*wv.x + uv.y*wv.y + uv.z*wv.z + uv.w*wv.w;
    }
  }
  #pragma unroll
  for (int e = 0; e < 9; ++e) xdbl[tok*40 + grp*9 + e] = acc[e];
  __syncthreads();

  {
    int tk = t >> 2, q = t & 3;
    float4 bv = *(const float4*)&xdbl[tk*40 + 4  + q*4];
    float4 cv = *(const float4*)&xdbl[tk*40 + 20 + q*4];
    *(float4*)&Bm[(tok0+tk)*16 + q*4] = bv;
    *(float4*)&Cm[(tok0+tk)*16 + q*4] = cv;
  }
  int d = t & 127, th = t >> 7;
  float w0 = wdtT[d], w1 = wdtT[128+d], w2 = wdtT[256+d], w3 = wdtT[384+d];
  float bias = db[d];
  for (int j = 0; j < 32; ++j) {
    int tk = th*32 + j;
    float a = bias + xdbl[tk*40]*w0 + xdbl[tk*40+1]*w1
                   + xdbl[tk*40+2]*w2 + xdbl[tk*40+3]*w3;
    dt[(tok0+tk)*128 + d] = softplus_f(a);
  }
}

// ---------------- K4A: per-chunk local scan -> carries. thread = (d = t>>1, s-half = t&1)
__global__ __launch_bounds__(256) void k4a_local(
    const float* __restrict__ dt, const float* __restrict__ u,
    const float* __restrict__ Bm, const float* __restrict__ Alog,
    float* __restrict__ carP, float* __restrict__ carH)
{
  int t = threadIdx.x;
  int d = t >> 1, sh = t & 1;
  int b = blockIdx.x / NCH, ch = blockIdx.x % NCH;
  long nb = (long)b*NTOK + (long)ch*CHL;
  float A[8], h[8], P[8];
  #pragma unroll
  for (int k = 0; k < 2; ++k) {
    float4 a = *(const float4*)&Alog[d*16 + sh*8 + k*4];
    A[k*4+0] = -__expf(a.x); A[k*4+1] = -__expf(a.y);
    A[k*4+2] = -__expf(a.z); A[k*4+3] = -__expf(a.w);
  }
  #pragma unroll
  for (int s = 0; s < 8; ++s) { h[s] = 0.f; P[s] = 1.f; }
  for (int i = 0; i < CHL; ++i) {
    long n = nb + i;
    float dtv = dt[n*128 + d];
    float uv  = u [n*128 + d];
    float du  = dtv * uv;
    float Bv[8];
    #pragma unroll
    for (int k = 0; k < 2; ++k) {
      float4 v = *(const float4*)&Bm[n*16 + sh*8 + k*4];
      Bv[k*4]=v.x; Bv[k*4+1]=v.y; Bv[k*4+2]=v.z; Bv[k*4+3]=v.w;
    }
    #pragma unroll
    for (int s = 0; s < 8; ++s) {
      float dA = __expf(dtv * A[s]);
      h[s] = dA*h[s] + du*Bv[s];
      P[s] *= dA;
    }
  }
  long cbs = ((long)(b*NCH + ch)*128 + d)*16 + sh*8;
  #pragma unroll
  for (int k = 0; k < 2; ++k) {
    *(float4*)&carP[cbs + k*4] = make_float4(P[k*4],P[k*4+1],P[k*4+2],P[k*4+3]);
    *(float4*)&carH[cbs + k*4] = make_float4(h[k*4],h[k*4+1],h[k*4+2],h[k*4+3]);
  }
}

// ---------------- K4B1: scan GCH-chunk groups; exclusive prefixes in place + group carries
__global__ __launch_bounds__(256) void k4b1_group(
    float* __restrict__ cP, float* __restrict__ cH,
    float* __restrict__ Pg, float* __restrict__ Hg)
{
  int idx = blockIdx.x*256 + threadIdx.x;
  int rem = idx & 2047;
  int g   = (idx >> 11) & (NG-1);
  int b   = idx >> 16;
  float P = 1.f, H = 0.f;
  long base = ((long)b*NCH + g*GCH)*2048 + rem;
  #pragma unroll 4
  for (int j = 0; j < GCH; ++j) {
    long a = base + (long)j*2048;
    float p = cP[a], h = cH[a];
    cP[a] = P; cH[a] = H;
    H = p*H + h;
    P = p*P;
  }
  long ga = ((long)b*NG + g)*2048 + rem;
  Pg[ga] = P; Hg[ga] = H;
}

// ---------------- K4B2: scan over NG group carries -> exclusive Hg in place
__global__ __launch_bounds__(256) void k4b2_carry(
    const float* __restrict__ Pg, float* __restrict__ Hg)
{
  int idx = blockIdx.x*256 + threadIdx.x;
  int b = idx >> 11, rem = idx & 2047;
  float H = 0.f;
  #pragma unroll 4
  for (int g = 0; g < NG; ++g) {
    long a = ((long)b*NG + g)*2048 + rem;
    float p = Pg[a], h = Hg[a];
    Hg[a] = H;
    H = p*H + h;
  }
}

// ---------------- K4C: chunk scan w/ carry-in + C-contraction + uD + *silu(z).
// thread = (d = t>>1, s-half = t&1); y combined via shfl_xor(1).
__global__ __launch_bounds__(256) void k4c_apply(
    const float* __restrict__ dt, const float* __restrict__ u,
    const float* __restrict__ Bm, const float* __restrict__ Cm,
    const float* __restrict__ Alog, const float* __restrict__ Dp,
    const float* __restrict__ zs, const float* __restrict__ pPre,
    const float* __restrict__ hPre, const float* __restrict__ Hg,
    float* __restrict__ yz)
{
  int t = threadIdx.x;
  int d = t >> 1, sh = t & 1;
  int b = blockIdx.x / NCH, ch = blockIdx.x % NCH;
  long nb = (long)b*NTOK + (long)ch*CHL;
  float A[8], h[8];
  #pragma unroll
  for (int k = 0; k < 2; ++k) {
    float4 a = *(const float4*)&Alog[d*16 + sh*8 + k*4];
    A[k*4+0] = -__expf(a.x); A[k*4+1] = -__expf(a.y);
    A[k*4+2] = -__expf(a.z); A[k*4+3] = -__expf(a.w);
  }
  long cbs = ((long)(b*NCH + ch)*128 + d)*16 + sh*8;
  long gbs = ((long)b*NG + (ch >> 4))*2048 + d*16 + sh*8;
  #pragma unroll
  for (int k = 0; k < 2; ++k) {
    float4 hp = *(const float4*)&hPre[cbs + k*4];
    float4 pp = *(const float4*)&pPre[cbs + k*4];
    float4 gi = *(const float4*)&Hg[gbs + k*4];
    h[k*4+0] = hp.x + pp.x*gi.x; h[k*4+1] = hp.y + pp.y*gi.y;
    h[k*4+2] = hp.z + pp.z*gi.z; h[k*4+3] = hp.w + pp.w*gi.w;
  }
  float Dv = Dp[d];
  for (int i = 0; i < CHL; ++i) {
    long n = nb + i;
    float dtv = dt[n*128 + d];
    float uv  = u [n*128 + d];
    float du  = dtv * uv;
    float Bv[8], Cv[8];
    #pragma unroll
    for (int k = 0; k < 2; ++k) {
      float4 v = *(const float4*)&Bm[n*16 + sh*8 + k*4];
      Bv[k*4]=v.x; Bv[k*4+1]=v.y; Bv[k*4+2]=v.z; Bv[k*4+3]=v.w;
      float4 w = *(const float4*)&Cm[n*16 + sh*8 + k*4];
      Cv[k*4]=w.x; Cv[k*4+1]=w.y; Cv[k*4+2]=w.z; Cv[k*4+3]=w.w;
    }
    float y = 0.f;
    #pragma unroll
    for (int s = 0; s < 8; ++s) {
      float dA = __expf(dtv * A[s]);
      h[s] = dA*h[s] + du*Bv[s];
      y += h[s]*Cv[s];
    }
    y += __shfl_xor(y, 1);
    if (sh == 0)
      yz[n*128 + d] = (y + uv*Dv) * zs[n*128 + d];
  }
}

// ---------------- K6: out_proj (128 -> 64) + bias, write (B,C,N)
__global__ __launch_bounds__(256) void k6_outproj(
    const float* __restrict__ yz, const float* __restrict__ Wout,
    const float* __restrict__ ob, float* __restrict__ out)
{
  __shared__ __align__(16) float wo[64*132];
  __shared__ __align__(16) float yl[32*132];
  int t = threadIdx.x;
  long tok0 = (long)blockIdx.x * 32;
  for (int i = 0; i < 8; ++i) {
    int g = i*256 + t; int c = g >> 5, q = g & 31;
    *(float4*)&wo[c*132 + q*4] = *(const float4*)&Wout[c*128 + q*4];
  }
  for (int i = 0; i < 4; ++i) {
    int g = i*256 + t; int tok = g >> 5, q = g & 31;
    *(float4*)&yl[tok*132 + q*4] = *(const float4*)&yz[(tok0 + tok)*128 + q*4];
  }
  __syncthreads();
  int tp = t & 15;
  int tg = t >> 4;
  float acc[4][2] = {{0.f}};
  for (int d4 = 0; d4 < 32; ++d4) {
    float4 y0 = *(const float4*)&yl[tg*132 + d4*4];
    float4 y1 = *(const float4*)&yl[(tg+16)*132 + d4*4];
    #pragma unroll
    for (int cc = 0; cc < 4; ++cc) {
      float4 wv = *(const float4*)&wo[(tp + 16*cc)*132 + d4*4];
      acc[cc][0] += wv.x*y0.x + wv.y*y0.y + wv.z*y0.z + wv.w*y0.w;
      acc[cc][1] += wv.x*y1.x + wv.y*y1.y + wv.z*y1.z + wv.w*y1.w;
    }
  }
  int b  = (int)(tok0 / NTOK);
  long n0 = tok0 % NTOK;
  #pragma unroll
  for (int cc = 0; cc < 4; ++cc) {
    int c = tp + 16*cc;
    float bias = ob[c];
    out[((long)b*64 + c)*NTOK + n0 + tg     ] = acc[cc][0] + bias;
    out[((long)b*64 + c)*NTOK + n0 + tg + 16] = acc[cc][1] + bias;
  }
}

extern "C" void kernel_launch(void* const* d_in, const int* in_sizes, int n_in,
                              void* d_out, int out_size, void* d_ws, size_t ws_size,
                              hipStream_t stream)
{
  (void)in_sizes; (void)n_in; (void)out_size; (void)ws_size;
  const float* x    = (const float*)d_in[0];
  const float* lnw  = (const float*)d_in[1];
  const float* lnb  = (const float*)d_in[2];
  const float* Win  = (const float*)d_in[3];
  const float* cw   = (const float*)d_in[4];
  const float* cb   = (const float*)d_in[5];
  const float* Wx   = (const float*)d_in[6];
  const float* Wdt  = (const float*)d_in[7];
  const float* db   = (const float*)d_in[8];
  const float* Alog = (const float*)d_in[9];
  const float* Dp   = (const float*)d_in[10];
  const float* Wout = (const float*)d_in[11];
  const float* ob   = (const float*)d_in[12];
  float* out = (float*)d_out;

  float* w   = (float*)d_ws;
  float* xin = w;                 // 4,194,304
  float* z   = w + 4194304;       // 4,194,304
  float* u   = w + 8388608;       // 4,194,304
  float* dt  = w + 12582912;      // 4,194,304
  float* Bm  = w + 16777216;      // 524,288
  float* Cm  = w + 17301504;      // 524,288
  float* cP  = w + 17825792;      // 2,097,152 (becomes exclusive P-prefix)
  float* cH  = w + 19922944;      // 2,097,152 (becomes exclusive h-prefix)
  float* Pg  = w + 22020096;      // 131,072
  float* Hg  = w + 22151168;      // 131,072
  float* yz  = w + 22282240;      // 4,194,304

  k1_ln_inproj<<<512, 256, 0, stream>>>(x, lnw, lnb, Win, xin, z);
  k2_conv     <<<2048,256, 0, stream>>>(xin, cw, cb, u);
  k3_xproj_dt <<<512, 256, 0, stream>>>(u, Wx, Wdt, db, dt, Bm, Cm);
  k4a_local   <<<1024,256, 0, stream>>>(dt, u, Bm, Alog, cP, cH);
  k4b1_group  <<<512, 256, 0, stream>>>(cP, cH, Pg, Hg);
  k4b2_carry  <<<16,  256, 0, stream>>>(Pg, Hg);
  k4c_apply   <<<1024,256, 0, stream>>>(dt, u, Bm, Cm, Alog, Dp, z, cP, cH, Hg, yz);
  k6_outproj  <<<1024,256, 0, stream>>>(yz, Wout, ob, out);
}